// Round 8
// baseline (313.660 us; speedup 1.0000x reference)
//
#include <hip/hip_runtime.h>
#include <math.h>

typedef unsigned short ushort_t;
typedef __attribute__((ext_vector_type(8))) short short8;
typedef __attribute__((ext_vector_type(4))) float f32x4;

#define NN    20000
#define DEG   16
constexpr int MAXL2 = 17;
constexpr int MAXL1 = 289;
constexpr int L0PAD = 73 * 64;   // 4672 padded logit rows; c1*16 <= 4624 fits

__device__ __forceinline__ ushort_t f2bf(float f) {
    unsigned u = __float_as_uint(f);
    return (ushort_t)((u + 0x7FFFu + ((u >> 16) & 1u)) >> 16);   // RTN-even
}
// hw packed f32x2 -> bf16x2 (RNE), gfx950
__device__ __forceinline__ unsigned pkbf(float lo, float hi) {
    unsigned r;
    asm("v_cvt_pk_bf16_f32 %0, %1, %2" : "=v"(r) : "v"(lo), "v"(hi));
    return r;
}

// ---------------- frontier (block 0: BFS 2+1) + tiny zero + aw0 transpose + L3 warming ---------
__global__ __launch_bounds__(256)
void k_frontier(const int* __restrict__ senders,
                int* __restrict__ list2, int* __restrict__ inv2,
                int* __restrict__ list1, int* __restrict__ inv1,
                int* __restrict__ cnts,
                const float* __restrict__ aw0, ushort_t* __restrict__ awT,
                const float* __restrict__ aw1,
                const float* __restrict__ lw1, const float* __restrict__ aw2,
                const float* __restrict__ lw2, const float* __restrict__ ow,
                float* __restrict__ dummy,
                float4* __restrict__ zp, int n4, int nzb) {
    int t = threadIdx.x;
    int bb = (int)blockIdx.x;
    if (bb > 0) {
        int b = bb - 1;
        if (b < nzb) {                       // zero lgc0 (atomic accumulator), ~19 KB
            int i = b * 256 + t;
            if (i < n4) zp[i] = make_float4(0.f, 0.f, 0.f, 0.f);
            return;
        }
        b -= nzb;
        if (b < 512) {                       // aw0 [1024][512] -> awT bf16 [512][1024]
            __shared__ float tile[32][33];
            int bx = b & 15, by = b >> 4;
            int i0 = t >> 3, j0 = (t & 7) * 4;
            float4 v = *(const float4*)(aw0 + (size_t)(by * 32 + i0) * 512 + bx * 32 + j0);
            tile[i0][j0] = v.x; tile[i0][j0 + 1] = v.y; tile[i0][j0 + 2] = v.z; tile[i0][j0 + 3] = v.w;
            __syncthreads();
            int n = bx * 32 + i0, kc = j0;
            ushort4 o;
            o.x = f2bf(tile[kc][i0]);     o.y = f2bf(tile[kc + 1][i0]);
            o.z = f2bf(tile[kc + 2][i0]); o.w = f2bf(tile[kc + 3][i0]);
            *(ushort4*)(awT + (size_t)n * 1024 + by * 32 + kc) = o;
            return;
        }
        b -= 512;
        // L3 warming: lw1(64) aw1(32) aw2(8) lw2(16) ow(4) blocks x 16 KB
        const float4* src; int base;
        if (b < 64)        { src = (const float4*)lw1; base = b * 1024; }
        else if (b < 96)   { src = (const float4*)aw1; base = (b - 64) * 1024; }
        else if (b < 104)  { src = (const float4*)aw2; base = (b - 96) * 1024; }
        else if (b < 120)  { src = (const float4*)lw2; base = (b - 104) * 1024; }
        else               { src = (const float4*)ow;  base = (b - 120) * 1024; }
        float s = 0.f;
#pragma unroll
        for (int i = 0; i < 4; i++) {
            float4 v = src[base + i * 256 + t];
            s += v.x + v.y + v.z + v.w;
        }
        if (s == 1234.5678f) dummy[0] = s;   // keep loads live
        return;
    }
    __shared__ unsigned bm[625];
    __shared__ int cnt;
    __shared__ int lloc[MAXL2];
    auto clear = [&]() { for (int i = t; i < 625; i += 256) bm[i] = 0u; if (t == 0) cnt = 0; };
    clear(); __syncthreads();
    if (t < 17) {
        int node = (t < 16) ? senders[14 * DEG + t] : 14;
        unsigned bit = 1u << (node & 31);
        unsigned old = atomicOr(&bm[node >> 5], bit);
        if (!(old & bit)) { int p = atomicAdd(&cnt, 1); list2[p] = node; inv2[node] = p; lloc[p] = node; }
    }
    __syncthreads();
    int c2 = cnt;
    if (t == 0) cnts[2] = c2;
    __syncthreads(); clear(); __syncthreads();
    for (int i = t; i < c2 * 17; i += 256) {
        int r = i / 17, k = i - r * 17;
        int node = (k < 16) ? senders[lloc[r] * DEG + k] : lloc[r];
        unsigned bit = 1u << (node & 31);
        unsigned old = atomicOr(&bm[node >> 5], bit);
        if (!(old & bit)) { int p = atomicAdd(&cnt, 1); list1[p] = node; inv1[node] = p; }
    }
    __syncthreads();
    if (t == 0) { int c1 = cnt; cnts[1] = c1; cnts[0] = c1 * 16; }
}

// ---------------- logits0: fused X-gather + bf16 cvt + MFMA GEMM + relu-dot epilogue -----------
// Row r of lgc0 == logit of node senders[list1[r>>4]*16 + (r&15)] (no inv0 needed downstream).
// Single 64-col tile, grid (73, 8) = 584 blocks (~9 waves/CU); depth-2 global prefetch.
// Split-K FORBIDDEN (relu of partials).
__global__ __launch_bounds__(256)
void k_logits0(const float* __restrict__ X, const int* __restrict__ senders,
               const int* __restrict__ list1, const ushort_t* __restrict__ WT,
               const float* __restrict__ aq, float* __restrict__ lgc,
               const int* __restrict__ cnt) {
    __shared__ short As[64 * 40];
    __shared__ short Bs[64 * 40];
    int rcnt = *cnt;                      // c1*16
    int row0 = blockIdx.x * 64;
    if (row0 >= rcnt) return;
    int col0 = blockIdx.y * 64;
    int t = threadIdx.x;
    int w = t >> 6, lane = t & 63;
    int sr = t >> 2, sk = (t & 3) * 8;

    int grow = row0 + sr;
    bool av = grow < rcnt;
    const float* xrow = X;
    if (av) {
        int n = list1[grow >> 4];
        int s = senders[n * DEG + (grow & 15)];
        xrow = X + (size_t)s * 1024;
    }
    const ushort_t* bp = WT + (size_t)(col0 + sr) * 1024 + sk;

    int fm = lane & 15, fq = lane >> 4;
    const short* arow = As + (w * 16 + fm) * 40 + fq * 8;
    const short* brow = Bs + fm * 40 + fq * 8;

    f32x4 acc0 = {0.f,0.f,0.f,0.f}, acc1 = {0.f,0.f,0.f,0.f};
    f32x4 acc2 = {0.f,0.f,0.f,0.f}, acc3 = {0.f,0.f,0.f,0.f};

    float4 z4 = make_float4(0.f, 0.f, 0.f, 0.f);
    // depth-2 prefetch: slot A holds K-step k0, slot B holds k0+32 (unrolled x2)
    float4 paA0 = av ? *(const float4*)(xrow + sk)          : z4;
    float4 paA1 = av ? *(const float4*)(xrow + sk + 4)      : z4;
    float4 paB0 = av ? *(const float4*)(xrow + 32 + sk)     : z4;
    float4 paB1 = av ? *(const float4*)(xrow + 32 + sk + 4) : z4;
    short8 pbA = *(const short8*)(bp);
    short8 pbB = *(const short8*)(bp + 32);

    short* asw = (short*)(As + sr * 40 + sk);
    short* bsw = (short*)(Bs + sr * 40 + sk);
    for (int k0 = 0; k0 < 1024; k0 += 64) {
        // ---- even half: consume slot A (K-step k0), refill for k0+64 ----
        *(uint4*)asw = make_uint4(pkbf(paA0.x, paA0.y), pkbf(paA0.z, paA0.w),
                                  pkbf(paA1.x, paA1.y), pkbf(paA1.z, paA1.w));
        *(short8*)bsw = pbA;
        __syncthreads();
        if (k0 + 64 < 1024) {
            paA0 = av ? *(const float4*)(xrow + k0 + 64 + sk)     : z4;
            paA1 = av ? *(const float4*)(xrow + k0 + 64 + sk + 4) : z4;
            pbA  = *(const short8*)(bp + k0 + 64);
        }
        {
            short8 af = *(const short8*)arow;
            short8 b0 = *(const short8*)(brow);
            short8 b1 = *(const short8*)(brow + 16 * 40);
            short8 b2 = *(const short8*)(brow + 32 * 40);
            short8 b3 = *(const short8*)(brow + 48 * 40);
            acc0 = __builtin_amdgcn_mfma_f32_16x16x32_bf16(af, b0, acc0, 0, 0, 0);
            acc1 = __builtin_amdgcn_mfma_f32_16x16x32_bf16(af, b1, acc1, 0, 0, 0);
            acc2 = __builtin_amdgcn_mfma_f32_16x16x32_bf16(af, b2, acc2, 0, 0, 0);
            acc3 = __builtin_amdgcn_mfma_f32_16x16x32_bf16(af, b3, acc3, 0, 0, 0);
        }
        __syncthreads();
        // ---- odd half: consume slot B (K-step k0+32), refill for k0+96 ----
        *(uint4*)asw = make_uint4(pkbf(paB0.x, paB0.y), pkbf(paB0.z, paB0.w),
                                  pkbf(paB1.x, paB1.y), pkbf(paB1.z, paB1.w));
        *(short8*)bsw = pbB;
        __syncthreads();
        if (k0 + 96 < 1024) {
            paB0 = av ? *(const float4*)(xrow + k0 + 96 + sk)     : z4;
            paB1 = av ? *(const float4*)(xrow + k0 + 96 + sk + 4) : z4;
            pbB  = *(const short8*)(bp + k0 + 96);
        }
        {
            short8 af = *(const short8*)arow;
            short8 b0 = *(const short8*)(brow);
            short8 b1 = *(const short8*)(brow + 16 * 40);
            short8 b2 = *(const short8*)(brow + 32 * 40);
            short8 b3 = *(const short8*)(brow + 48 * 40);
            acc0 = __builtin_amdgcn_mfma_f32_16x16x32_bf16(af, b0, acc0, 0, 0, 0);
            acc1 = __builtin_amdgcn_mfma_f32_16x16x32_bf16(af, b1, acc1, 0, 0, 0);
            acc2 = __builtin_amdgcn_mfma_f32_16x16x32_bf16(af, b2, acc2, 0, 0, 0);
            acc3 = __builtin_amdgcn_mfma_f32_16x16x32_bf16(af, b3, acc3, 0, 0, 0);
        }
        __syncthreads();
    }

    float aqv0 = aq[col0 + fm],      aqv1 = aq[col0 + 16 + fm];
    float aqv2 = aq[col0 + 32 + fm], aqv3 = aq[col0 + 48 + fm];
#pragma unroll
    for (int r = 0; r < 4; r++) {
        float v = fmaxf(acc0[r], 0.f) * aqv0 + fmaxf(acc1[r], 0.f) * aqv1
                + fmaxf(acc2[r], 0.f) * aqv2 + fmaxf(acc3[r], 0.f) * aqv3;
#pragma unroll
        for (int off = 1; off < 16; off <<= 1) v += __shfl_xor(v, off);
        if (fm == 0) atomicAdd(&lgc[row0 + w * 16 + fq * 4 + r], v);
    }
}

// ---------------- layer-0 attention aggregate -> hN0 (lgc0 rows b*16+k, no inv0) ---------------
__global__ __launch_bounds__(256)
void k_agg0(const float* __restrict__ X, const float* __restrict__ lgc0,
            const int* __restrict__ senders, const int* __restrict__ list1,
            const int* __restrict__ cnt1, float* __restrict__ hN0) {
    __shared__ int   s_row[DEG];
    __shared__ float s_w[DEG];
    __shared__ float s_sc;
    int b = blockIdx.x;
    if (b >= *cnt1) return;
    int t = threadIdx.x;
    if (t < DEG) {
        s_row[t] = senders[list1[b] * DEG + t];
        s_w[t]   = lgc0[b * DEG + t];
    }
    __syncthreads();
    if (t == 0) {
        float m = -1e30f;
        for (int k = 0; k < DEG; k++) m = fmaxf(m, s_w[k]);
        float d = 0.f;
        for (int k = 0; k < DEG; k++) { float w = __expf(s_w[k] - m); s_w[k] = w; d += w; }
        s_sc = 1.f / d;
    }
    __syncthreads();
    float scale = s_sc;
    int dI = t * 4;
    float4 acc = make_float4(0.f, 0.f, 0.f, 0.f);
#pragma unroll
    for (int k = 0; k < DEG; k++) {
        float w = s_w[k];
        float4 v = *(const float4*)(X + (size_t)s_row[k] * 1024 + dI);
        acc.x += w * v.x; acc.y += w * v.y; acc.z += w * v.z; acc.w += w * v.w;
    }
    acc.x *= scale; acc.y *= scale; acc.z *= scale; acc.w *= scale;
    *(float4*)(hN0 + (size_t)b * 1024 + dI) = acc;
}

// ---------------- mm0: C0p[z] = [X|hN0]@lw0 k-slice z (split-K 16, direct stores) --------------
__global__ __launch_bounds__(256)
void k_mm0(const float* __restrict__ X, const float* __restrict__ hN0,
           const int* __restrict__ list1, const float* __restrict__ B,
           float* __restrict__ C0p, const int* __restrict__ cnt) {
    __shared__ float As[32][68];
    __shared__ float Bs[32][64];
    int rcnt = *cnt;
    int row0 = blockIdx.x * 64;
    if (row0 >= rcnt) return;
    int col0 = blockIdx.y * 64;
    int kbeg = blockIdx.z * 128;
    int t = threadIdx.x;
    int ty = t >> 4, tx = t & 15;
    int lr = t >> 2, kaoff = (t & 3) * 4;
    int grow = row0 + lr;
    bool rowValid = grow < rcnt;
    const float* rp;
    if (kbeg < 1024) rp = rowValid ? X + (size_t)list1[grow] * 1024 + kbeg : X;
    else             rp = rowValid ? hN0 + (size_t)grow * 1024 + (kbeg - 1024) : hN0;
    const float* Bp = B + (size_t)kbeg * 512 + col0;
    int bidx0 = t, bidx1 = t + 256;

    auto loadA = [&](int k) -> float4 {
        if (!rowValid) return make_float4(0.f, 0.f, 0.f, 0.f);
        return *(const float4*)(rp + k);
    };
    auto loadB = [&](int idx, int k0) -> float4 {
        int row = idx >> 4, c4 = (idx & 15) * 4;
        return *(const float4*)(Bp + (size_t)(k0 + row) * 512 + c4);
    };

    float4 pa0 = loadA(kaoff);
    float4 pa1 = loadA(kaoff + 16);
    float4 pb0 = loadB(bidx0, 0);
    float4 pb1 = loadB(bidx1, 0);

    float acc[4][4] = {};
    for (int k0 = 0; k0 < 128; k0 += 32) {
        As[kaoff + 0][lr] = pa0.x; As[kaoff + 1][lr] = pa0.y;
        As[kaoff + 2][lr] = pa0.z; As[kaoff + 3][lr] = pa0.w;
        As[kaoff + 16][lr] = pa1.x; As[kaoff + 17][lr] = pa1.y;
        As[kaoff + 18][lr] = pa1.z; As[kaoff + 19][lr] = pa1.w;
        *(float4*)&Bs[bidx0 >> 4][(bidx0 & 15) * 4] = pb0;
        *(float4*)&Bs[bidx1 >> 4][(bidx1 & 15) * 4] = pb1;
        __syncthreads();
        if (k0 + 32 < 128) {
            pa0 = loadA(k0 + 32 + kaoff);
            pa1 = loadA(k0 + 32 + kaoff + 16);
            pb0 = loadB(bidx0, k0 + 32);
            pb1 = loadB(bidx1, k0 + 32);
        }
#pragma unroll
        for (int kk = 0; kk < 32; kk++) {
            float4 a4 = *(const float4*)&As[kk][ty * 4];
            float4 b4 = *(const float4*)&Bs[kk][tx * 4];
            float a[4] = {a4.x, a4.y, a4.z, a4.w};
            float b[4] = {b4.x, b4.y, b4.z, b4.w};
#pragma unroll
            for (int i = 0; i < 4; i++)
#pragma unroll
                for (int j = 0; j < 4; j++) acc[i][j] += a[i] * b[j];
        }
        __syncthreads();
    }
#pragma unroll
    for (int i = 0; i < 4; i++) {
        int r = row0 + ty * 4 + i;
        if (r < rcnt) {
            float* Crow = C0p + ((size_t)blockIdx.z * MAXL1 + r) * 512 + col0 + tx * 4;
            *(float4*)Crow = make_float4(acc[i][0], acc[i][1], acc[i][2], acc[i][3]);
        }
    }
}

// ---------------- fused split-K reduce + bias + relu -> h1, fp32 layer-1 logits -> lgc1 --------
__global__ __launch_bounds__(256)
void k_bias_logits(const float* __restrict__ C0p, const float* __restrict__ lb0,
                   const float* __restrict__ aw1, const float* __restrict__ aq1,
                   float* __restrict__ h1, float* __restrict__ lgc1,
                   const int* __restrict__ cnt) {
    __shared__ float sh[512];
    __shared__ float red[4];
    int r = blockIdx.x;
    if (r >= *cnt) return;
    int t = threadIdx.x;
    float v0 = lb0[t], v1 = lb0[256 + t];
    const float* base = C0p + (size_t)r * 512;
#pragma unroll
    for (int z = 0; z < 16; z++) {
        v0 += base[(size_t)z * MAXL1 * 512 + t];
        v1 += base[(size_t)z * MAXL1 * 512 + 256 + t];
    }
    v0 = v0 > 0.f ? v0 : 0.f;
    v1 = v1 > 0.f ? v1 : 0.f;
    sh[t] = v0; sh[256 + t] = v1;
    h1[(size_t)r * 512 + t] = v0;
    h1[(size_t)r * 512 + 256 + t] = v1;
    __syncthreads();
    float dot = 0.f;
    for (int k = 0; k < 512; k += 4) {
        dot += sh[k + 0] * aw1[(size_t)(k + 0) * 256 + t]
             + sh[k + 1] * aw1[(size_t)(k + 1) * 256 + t]
             + sh[k + 2] * aw1[(size_t)(k + 2) * 256 + t]
             + sh[k + 3] * aw1[(size_t)(k + 3) * 256 + t];
    }
    float v = (dot > 0.f ? dot : 0.f) * aq1[t];
#pragma unroll
    for (int off = 1; off < 64; off <<= 1) v += __shfl_xor(v, off);
    if ((t & 63) == 0) red[t >> 6] = v;
    __syncthreads();
    if (t == 0) lgc1[r] = red[0] + red[1] + red[2] + red[3];
}

// ---------------- fused layer-1 tail: softmax(lgc1) agg + [h1|hN1]@lw1 + bias + relu -> h2 -----
// 16 blocks x 16 output cols; 16 k-slices x 64 over K=1024.
__global__ __launch_bounds__(256)
void k_tail1(const float* __restrict__ h1, const float* __restrict__ lgc1,
             const int* __restrict__ senders, const int* __restrict__ list2,
             const int* __restrict__ inv1, const int* __restrict__ cnts,
             const float* __restrict__ lw1, const float* __restrict__ lb1,
             float* __restrict__ h2) {
    __shared__ __align__(16) float As[17][1024];  // [j][0:512)=own h1 row, [512:1024)=hN1 row
    __shared__ float sw[17][16];
    __shared__ int   srow[17][16];
    __shared__ int   orow[17];
    __shared__ float psum[16][17 * 16];
    int c2 = cnts[2];
    int t = threadIdx.x;
    int b = blockIdx.x;

    for (int i = t; i < c2 * 16; i += 256) {
        int j = i >> 4, k = i & 15;
        int s = senders[list2[j] * DEG + k];
        int rr = inv1[s];
        srow[j][k] = rr;
        sw[j][k] = lgc1[rr];
    }
    if (t < c2) orow[t] = inv1[list2[t]];
    __syncthreads();
    if (t < c2) {
        float m = -1e30f;
        for (int k = 0; k < 16; k++) m = fmaxf(m, sw[t][k]);
        float d = 0.f;
        for (int k = 0; k < 16; k++) { float w = __expf(sw[t][k] - m); sw[t][k] = w; d += w; }
        float inv = 1.f / d;
        for (int k = 0; k < 16; k++) sw[t][k] *= inv;
    }
    __syncthreads();
    for (int e = t; e < c2 * 128; e += 256) {
        int j = e >> 7, d4 = (e & 127) * 4;
        *(float4*)&As[j][d4] = *(const float4*)&h1[(size_t)orow[j] * 512 + d4];
        float4 a = make_float4(0.f, 0.f, 0.f, 0.f);
#pragma unroll
        for (int k = 0; k < 16; k++) {
            float w = sw[j][k];
            float4 v = *(const float4*)&h1[(size_t)srow[j][k] * 512 + d4];
            a.x += w * v.x; a.y += w * v.y; a.z += w * v.z; a.w += w * v.w;
        }
        *(float4*)&As[j][512 + d4] = a;
    }
    __syncthreads();
    // GEMM: thread = (col c 0..15, k-slice s 0..15 of 64)
    int c = t & 15, s = t >> 4;
    int gc = b * 16 + c;
    float acc[17];
#pragma unroll
    for (int j = 0; j < 17; j++) acc[j] = 0.f;
    for (int k = s * 64; k < s * 64 + 64; k += 4) {
        float b0 = lw1[(size_t)(k + 0) * 256 + gc];
        float b1 = lw1[(size_t)(k + 1) * 256 + gc];
        float b2 = lw1[(size_t)(k + 2) * 256 + gc];
        float b3 = lw1[(size_t)(k + 3) * 256 + gc];
#pragma unroll
        for (int j = 0; j < 17; j++) {
            float4 a = *(const float4*)&As[j][k];
            acc[j] += a.x * b0 + a.y * b1 + a.z * b2 + a.w * b3;
        }
    }
#pragma unroll
    for (int j = 0; j < 17; j++) psum[s][j * 16 + c] = acc[j];
    __syncthreads();
    for (int e = t; e < c2 * 16; e += 256) {
        int j = e >> 4, cc = e & 15;
        float v = 0.f;
#pragma unroll
        for (int s2 = 0; s2 < 16; s2++) v += psum[s2][j * 16 + cc];
        v += lb1[b * 16 + cc];
        h2[(size_t)j * 256 + b * 16 + cc] = v > 0.f ? v : 0.f;
    }
}

// ---------------- fused layer-2 tail: logits2 + softmax + agg + [h2|hN2]@lw2 + out matvec ------
__global__ __launch_bounds__(512)
void k_tail2(const float* __restrict__ h2, const int* __restrict__ senders,
             const int* __restrict__ inv2, const int* __restrict__ cnts,
             const float* __restrict__ aw2, const float* __restrict__ aq2,
             const float* __restrict__ lw2, const float* __restrict__ lb2,
             const float* __restrict__ ow, const float* __restrict__ ob,
             float* __restrict__ out) {
    __shared__ __align__(16) float sh2[17][256];
    __shared__ __align__(16) float psum[8][17][128];
    __shared__ __align__(16) float h3in[512];
    __shared__ __align__(16) float sh3[128];
    __shared__ __align__(16) float psumB[16][128];
    __shared__ float slog[17];
    __shared__ float swt[16];
    __shared__ int   srow2[16];
    __shared__ int   srow14;
    int c2 = cnts[2];
    int t = threadIdx.x;
    for (int e = t; e < c2 * 64; e += 512) {
        int j = e >> 6, d4 = (e & 63) * 4;
        *(float4*)&sh2[j][d4] = *(const float4*)&h2[(size_t)j * 256 + d4];
    }
    if (t < c2) slog[t] = 0.f;
    if (t < 16) srow2[t] = inv2[senders[14 * DEG + t]];
    if (t == 31) srow14 = inv2[14];
    __syncthreads();
    {
        int cg = t & 31;
        int s  = (t >> 5) & 7;
        int jg = t >> 8;
        int j0 = jg * 9;
        int jend = min(c2, j0 + 9);
        float4 acc[9];
#pragma unroll
        for (int i = 0; i < 9; i++) acc[i] = make_float4(0.f, 0.f, 0.f, 0.f);
        const float* ap = aw2 + cg * 4;
        for (int k = s * 32; k < s * 32 + 32; k++) {
            float4 bv = *(const float4*)(ap + (size_t)k * 128);
#pragma unroll
            for (int i = 0; i < 9; i++) {
                int j = j0 + i;
                if (j < jend) {
                    float a = sh2[j][k];
                    acc[i].x += a * bv.x; acc[i].y += a * bv.y;
                    acc[i].z += a * bv.z; acc[i].w += a * bv.w;
                }
            }
        }
#pragma unroll
        for (int i = 0; i < 9; i++) {
            int j = j0 + i;
            if (j < jend) *(float4*)&psum[s][j][cg * 4] = acc[i];
        }
    }
    __syncthreads();
    for (int e = t; e < c2 * 128; e += 512) {
        int j = e >> 7, c = e & 127;
        float v = 0.f;
#pragma unroll
        for (int s = 0; s < 8; s++) v += psum[s][j][c];
        v = v > 0.f ? v : 0.f;
        atomicAdd(&slog[j], v * aq2[c]);
    }
    __syncthreads();
    if (t == 0) {
        float m = -1e30f;
        for (int k = 0; k < 16; k++) m = fmaxf(m, slog[srow2[k]]);
        float d = 0.f;
        for (int k = 0; k < 16; k++) { float w = __expf(slog[srow2[k]] - m); swt[k] = w; d += w; }
        float inv = 1.f / d;
        for (int k = 0; k < 16; k++) swt[k] *= inv;
    }
    __syncthreads();
    if (t < 256) {
        float a = 0.f;
#pragma unroll
        for (int k = 0; k < 16; k++) a += swt[k] * sh2[srow2[k]][t];
        h3in[256 + t] = a;
    } else {
        int d = t - 256;
        h3in[d] = sh2[srow14][d];
    }
    __syncthreads();
    {
        int cg = t & 31, s = t >> 5;
        float4 acc = make_float4(0.f, 0.f, 0.f, 0.f);
        const float* bp = lw2 + cg * 4;
        for (int k = s * 32; k < s * 32 + 32; k++) {
            float4 bv = *(const float4*)(bp + (size_t)k * 128);
            float a = h3in[k];
            acc.x += a * bv.x; acc.y += a * bv.y; acc.z += a * bv.z; acc.w += a * bv.w;
        }
        *(float4*)&psumB[s][cg * 4] = acc;
    }
    __syncthreads();
    if (t < 128) {
        float v = lb2[t];
#pragma unroll
        for (int s = 0; s < 16; s++) v += psumB[s][t];
        sh3[t] = v > 0.f ? v : 0.f;
    }
    __syncthreads();
    {
        int cg = t & 31, s = t >> 5;
        float4 acc = make_float4(0.f, 0.f, 0.f, 0.f);
        const float* bp = ow + cg * 4;
        for (int k = s * 8; k < s * 8 + 8; k++) {
            float4 bv = *(const float4*)(bp + (size_t)k * 128);
            float a = sh3[k];
            acc.x += a * bv.x; acc.y += a * bv.y; acc.z += a * bv.z; acc.w += a * bv.w;
        }
        *(float4*)&psumB[s][cg * 4] = acc;
    }
    __syncthreads();
    if (t < 128) {
        float v = ob[t];
#pragma unroll
        for (int s = 0; s < 16; s++) v += psumB[s][t];
        out[t] = v;
    }
}

// ---------------- launch ----------------
extern "C" void kernel_launch(void* const* d_in, const int* in_sizes, int n_in,
                              void* d_out, int out_size, void* d_ws, size_t ws_size,
                              hipStream_t stream) {
    const float* X       = (const float*)d_in[0];
    const int*   senders = (const int*)d_in[1];
    const float* lw0 = (const float*)d_in[3];
    const float* lb0 = (const float*)d_in[4];
    const float* aw0 = (const float*)d_in[5];
    const float* aq0 = (const float*)d_in[6];
    const float* lw1 = (const float*)d_in[7];
    const float* lb1 = (const float*)d_in[8];
    const float* aw1 = (const float*)d_in[9];
    const float* aq1 = (const float*)d_in[10];
    const float* lw2 = (const float*)d_in[11];
    const float* lb2 = (const float*)d_in[12];
    const float* aw2 = (const float*)d_in[13];
    const float* aq2 = (const float*)d_in[14];
    const float* owp = (const float*)d_in[15];
    const float* obp = (const float*)d_in[16];
    float* out = (float*)d_out;

    char* ws = (char*)d_ws;
    size_t off = 0;
    auto alloc = [&](size_t nbytes) -> void* {
        void* p = ws + off;
        off += (nbytes + 255) & ~(size_t)255;
        return p;
    };
    // ---- zero region (zeroed by k_frontier): lgc0 only ----
    float* lgc0 = (float*)alloc(L0PAD * 4);
    size_t zero_end = off;
    // ---- rest (poisoned; every read site written first) ----
    float* lgc1 = (float*)alloc(MAXL1 * 4);
    int* inv1  = (int*)alloc(NN * 4);
    int* inv2  = (int*)alloc(NN * 4);
    int* list1 = (int*)alloc(MAXL1 * 4);
    int* list2 = (int*)alloc(MAXL2 * 4);
    int* cnts  = (int*)alloc(16);
    float* dummy = (float*)alloc(16);
    ushort_t* awT = (ushort_t*)alloc((size_t)512 * 1024 * 2);      // aw0^T bf16 [512][1024]
    float* C0p  = (float*)alloc((size_t)16 * MAXL1 * 512 * 4);     // split-K partials
    float* hN0c = (float*)alloc((size_t)MAXL1 * 1024 * 4);
    float* h1c  = (float*)alloc((size_t)MAXL1 * 512 * 4);
    float* h2c  = (float*)alloc((size_t)MAXL2 * 256 * 4);
    (void)in_sizes; (void)n_in; (void)out_size; (void)ws_size;

    int nz4 = (int)(zero_end / 16);
    int nzb = (nz4 + 255) / 256;

    // 1. BFS 2+1 || zero lgc0 || transpose aw0 || warm tail weights
    hipLaunchKernelGGL(k_frontier, dim3(1 + nzb + 512 + 124), dim3(256), 0, stream,
                       senders, list2, inv2, list1, inv1, cnts,
                       aw0, awT, aw1, lw1, aw2, lw2, owp, dummy,
                       (float4*)ws, nz4, nzb);
    // 2. layer-0 logits: fused gather + bf16 MFMA (K=1024, single 64-col tile, 584 blocks)
    hipLaunchKernelGGL(k_logits0, dim3(73, 8), dim3(256), 0, stream,
                       X, senders, list1, awT, aq0, lgc0, cnts + 0);
    // 3. layer-0 attention aggregate
    hipLaunchKernelGGL(k_agg0, dim3(MAXL1), dim3(256), 0, stream,
                       X, lgc0, senders, list1, cnts + 1, hN0c);
    // 4. mm0: [X|hN0] @ lw0, split-K 16, direct partial stores
    hipLaunchKernelGGL(k_mm0, dim3(5, 8, 16), dim3(256), 0, stream,
                       X, hN0c, list1, lw0, C0p, cnts + 1);
    // 5. fused reduce + bias + relu -> h1, fp32 layer-1 logits -> lgc1
    hipLaunchKernelGGL(k_bias_logits, dim3(MAXL1), dim3(256), 0, stream,
                       C0p, lb0, aw1, aq1, h1c, lgc1, cnts + 1);
    // 6. fused layer-1 tail -> h2 (17x256)
    hipLaunchKernelGGL(k_tail1, dim3(16), dim3(256), 0, stream,
                       h1c, lgc1, senders, list2, inv1, cnts, lw1, lb1, h2c);
    // 7. fused layer-2 tail -> out (128)
    hipLaunchKernelGGL(k_tail2, dim3(1), dim3(512), 0, stream,
                       h2c, senders, inv2, cnts, aw2, aq2, lw2, lb2, owp, obp, out);
}

// Round 9
// 245.934 us; speedup vs baseline: 1.2754x; 1.2754x over previous
//
#include <hip/hip_runtime.h>
#include <math.h>

typedef unsigned short ushort_t;
typedef __attribute__((ext_vector_type(8))) short short8;
typedef __attribute__((ext_vector_type(4))) float f32x4;

#define NN    20000
#define DEG   16
constexpr int MAXL2 = 17;
constexpr int MAXL1 = 289;
constexpr int L0PAD = 73 * 64;   // 4672 padded logit rows; c1*16 <= 4624 fits

__device__ __forceinline__ ushort_t f2bf(float f) {
    unsigned u = __float_as_uint(f);
    return (ushort_t)((u + 0x7FFFu + ((u >> 16) & 1u)) >> 16);   // RTN-even
}

// ---------------- frontier (block 0: BFS 2+1) + tiny zero + aw0 transpose + L3 warming ---------
__global__ __launch_bounds__(256)
void k_frontier(const int* __restrict__ senders,
                int* __restrict__ list2, int* __restrict__ inv2,
                int* __restrict__ list1, int* __restrict__ inv1,
                int* __restrict__ cnts,
                const float* __restrict__ aw0, ushort_t* __restrict__ awT,
                const float* __restrict__ aw1,
                const float* __restrict__ lw1, const float* __restrict__ aw2,
                const float* __restrict__ lw2, const float* __restrict__ ow,
                float* __restrict__ dummy,
                float4* __restrict__ zp, int n4, int nzb) {
    int t = threadIdx.x;
    int bb = (int)blockIdx.x;
    if (bb > 0) {
        int b = bb - 1;
        if (b < nzb) {                       // zero lgc0 (atomic accumulator), ~19 KB
            int i = b * 256 + t;
            if (i < n4) zp[i] = make_float4(0.f, 0.f, 0.f, 0.f);
            return;
        }
        b -= nzb;
        if (b < 512) {                       // aw0 [1024][512] -> awT bf16 [512][1024]
            __shared__ float tile[32][33];
            int bx = b & 15, by = b >> 4;
            int i0 = t >> 3, j0 = (t & 7) * 4;
            float4 v = *(const float4*)(aw0 + (size_t)(by * 32 + i0) * 512 + bx * 32 + j0);
            tile[i0][j0] = v.x; tile[i0][j0 + 1] = v.y; tile[i0][j0 + 2] = v.z; tile[i0][j0 + 3] = v.w;
            __syncthreads();
            int n = bx * 32 + i0, kc = j0;
            ushort4 o;
            o.x = f2bf(tile[kc][i0]);     o.y = f2bf(tile[kc + 1][i0]);
            o.z = f2bf(tile[kc + 2][i0]); o.w = f2bf(tile[kc + 3][i0]);
            *(ushort4*)(awT + (size_t)n * 1024 + by * 32 + kc) = o;
            return;
        }
        b -= 512;
        // L3 warming: lw1(64) aw1(32) aw2(8) lw2(16) ow(4) blocks x 16 KB
        const float4* src; int base;
        if (b < 64)        { src = (const float4*)lw1; base = b * 1024; }
        else if (b < 96)   { src = (const float4*)aw1; base = (b - 64) * 1024; }
        else if (b < 104)  { src = (const float4*)aw2; base = (b - 96) * 1024; }
        else if (b < 120)  { src = (const float4*)lw2; base = (b - 104) * 1024; }
        else               { src = (const float4*)ow;  base = (b - 120) * 1024; }
        float s = 0.f;
#pragma unroll
        for (int i = 0; i < 4; i++) {
            float4 v = src[base + i * 256 + t];
            s += v.x + v.y + v.z + v.w;
        }
        if (s == 1234.5678f) dummy[0] = s;   // keep loads live
        return;
    }
    __shared__ unsigned bm[625];
    __shared__ int cnt;
    __shared__ int lloc[MAXL2];
    auto clear = [&]() { for (int i = t; i < 625; i += 256) bm[i] = 0u; if (t == 0) cnt = 0; };
    clear(); __syncthreads();
    if (t < 17) {
        int node = (t < 16) ? senders[14 * DEG + t] : 14;
        unsigned bit = 1u << (node & 31);
        unsigned old = atomicOr(&bm[node >> 5], bit);
        if (!(old & bit)) { int p = atomicAdd(&cnt, 1); list2[p] = node; inv2[node] = p; lloc[p] = node; }
    }
    __syncthreads();
    int c2 = cnt;
    if (t == 0) cnts[2] = c2;
    __syncthreads(); clear(); __syncthreads();
    for (int i = t; i < c2 * 17; i += 256) {
        int r = i / 17, k = i - r * 17;
        int node = (k < 16) ? senders[lloc[r] * DEG + k] : lloc[r];
        unsigned bit = 1u << (node & 31);
        unsigned old = atomicOr(&bm[node >> 5], bit);
        if (!(old & bit)) { int p = atomicAdd(&cnt, 1); list1[p] = node; inv1[node] = p; }
    }
    __syncthreads();
    if (t == 0) { int c1 = cnt; cnts[1] = c1; cnts[0] = c1 * 16; }
}

// ---------------- gather X rows -> bf16 Xg (row r = sender k of receiver list1[r>>4]) ----------
// No dedup, no inv0: duplicates cost ~13% extra GEMM rows; pad rows zeroed (guard-free MFMA).
__global__ __launch_bounds__(256)
void k_prep(const float* __restrict__ X, const int* __restrict__ senders,
            const int* __restrict__ list1, const int* __restrict__ cnts,
            ushort_t* __restrict__ Xg) {
    int r = blockIdx.x;
    int t = threadIdx.x;
    int rc = cnts[0];
    ushort4 o = make_ushort4(0, 0, 0, 0);
    if (r < rc) {
        int n = list1[r >> 4];                 // broadcast load
        int s = senders[n * DEG + (r & 15)];
        float4 v = *(const float4*)(X + (size_t)s * 1024 + t * 4);
        o.x = f2bf(v.x); o.y = f2bf(v.y); o.z = f2bf(v.z); o.w = f2bf(v.w);
    }
    *(ushort4*)(Xg + (size_t)r * 1024 + t * 4) = o;
}

// ---------------- logits0 bf16 MFMA GEMM over staged Xg (single 64-col tile, grid 73x8) --------
// lgc[r] += sum_c relu(Xg[r]@awT)[c]*aq[c].  Split-K FORBIDDEN (relu of partials).
__global__ __launch_bounds__(256)
void k_logits_mfma(const ushort_t* __restrict__ Xg,  // [L0PAD][1024]
                   const ushort_t* __restrict__ WT,  // [512][1024]
                   const float* __restrict__ aq, float* __restrict__ lgc,
                   const int* __restrict__ cnt) {
    __shared__ short As[64 * 40];
    __shared__ short Bs[64 * 40];
    int rcnt = *cnt;
    int row0 = blockIdx.x * 64;
    if (row0 >= rcnt) return;
    int col0 = blockIdx.y * 64;
    int t = threadIdx.x;
    int w = t >> 6, lane = t & 63;

    int sr = t >> 2, sk = (t & 3) * 8;
    const ushort_t* ap = Xg + (size_t)(row0 + sr) * 1024 + sk;
    const ushort_t* bp = WT + (size_t)(col0 + sr) * 1024 + sk;

    int fm = lane & 15, fq = lane >> 4;
    const short* arow = As + (w * 16 + fm) * 40 + fq * 8;
    const short* brow = Bs + fm * 40 + fq * 8;

    f32x4 acc0 = {0.f,0.f,0.f,0.f}, acc1 = {0.f,0.f,0.f,0.f};
    f32x4 acc2 = {0.f,0.f,0.f,0.f}, acc3 = {0.f,0.f,0.f,0.f};

    short8 pa = *(const short8*)(ap);
    short8 pb = *(const short8*)(bp);
    for (int k0 = 0; k0 < 1024; k0 += 32) {
        *(short8*)(As + sr * 40 + sk) = pa;
        *(short8*)(Bs + sr * 40 + sk) = pb;
        __syncthreads();
        if (k0 + 32 < 1024) {
            pa = *(const short8*)(ap + k0 + 32);
            pb = *(const short8*)(bp + k0 + 32);
        }
        short8 af = *(const short8*)arow;
        short8 b0 = *(const short8*)(brow);
        short8 b1 = *(const short8*)(brow + 16 * 40);
        short8 b2 = *(const short8*)(brow + 32 * 40);
        short8 b3 = *(const short8*)(brow + 48 * 40);
        acc0 = __builtin_amdgcn_mfma_f32_16x16x32_bf16(af, b0, acc0, 0, 0, 0);
        acc1 = __builtin_amdgcn_mfma_f32_16x16x32_bf16(af, b1, acc1, 0, 0, 0);
        acc2 = __builtin_amdgcn_mfma_f32_16x16x32_bf16(af, b2, acc2, 0, 0, 0);
        acc3 = __builtin_amdgcn_mfma_f32_16x16x32_bf16(af, b3, acc3, 0, 0, 0);
        __syncthreads();
    }

    float aqv0 = aq[col0 + fm],      aqv1 = aq[col0 + 16 + fm];
    float aqv2 = aq[col0 + 32 + fm], aqv3 = aq[col0 + 48 + fm];
#pragma unroll
    for (int r = 0; r < 4; r++) {
        float v = fmaxf(acc0[r], 0.f) * aqv0 + fmaxf(acc1[r], 0.f) * aqv1
                + fmaxf(acc2[r], 0.f) * aqv2 + fmaxf(acc3[r], 0.f) * aqv3;
#pragma unroll
        for (int off = 1; off < 16; off <<= 1) v += __shfl_xor(v, off);
        if (fm == 0) atomicAdd(&lgc[row0 + w * 16 + fq * 4 + r], v);
    }
}

// ---------------- layer-0 attention aggregate -> hN0 (lgc0 rows b*16+k, no inv0) ---------------
__global__ __launch_bounds__(256)
void k_agg0(const float* __restrict__ X, const float* __restrict__ lgc0,
            const int* __restrict__ senders, const int* __restrict__ list1,
            const int* __restrict__ cnt1, float* __restrict__ hN0) {
    __shared__ int   s_row[DEG];
    __shared__ float s_w[DEG];
    __shared__ float s_sc;
    int b = blockIdx.x;
    if (b >= *cnt1) return;
    int t = threadIdx.x;
    if (t < DEG) {
        s_row[t] = senders[list1[b] * DEG + t];
        s_w[t]   = lgc0[b * DEG + t];
    }
    __syncthreads();
    if (t == 0) {
        float m = -1e30f;
        for (int k = 0; k < DEG; k++) m = fmaxf(m, s_w[k]);
        float d = 0.f;
        for (int k = 0; k < DEG; k++) { float w = __expf(s_w[k] - m); s_w[k] = w; d += w; }
        s_sc = 1.f / d;
    }
    __syncthreads();
    float scale = s_sc;
    int dI = t * 4;
    float4 acc = make_float4(0.f, 0.f, 0.f, 0.f);
#pragma unroll
    for (int k = 0; k < DEG; k++) {
        float w = s_w[k];
        float4 v = *(const float4*)(X + (size_t)s_row[k] * 1024 + dI);
        acc.x += w * v.x; acc.y += w * v.y; acc.z += w * v.z; acc.w += w * v.w;
    }
    acc.x *= scale; acc.y *= scale; acc.z *= scale; acc.w *= scale;
    *(float4*)(hN0 + (size_t)b * 1024 + dI) = acc;
}

// ---------------- mm0: C0p[z] = [X|hN0]@lw0 k-slice z (split-K 16, direct stores) --------------
__global__ __launch_bounds__(256)
void k_mm0(const float* __restrict__ X, const float* __restrict__ hN0,
           const int* __restrict__ list1, const float* __restrict__ B,
           float* __restrict__ C0p, const int* __restrict__ cnt) {
    __shared__ float As[32][68];
    __shared__ float Bs[32][64];
    int rcnt = *cnt;
    int row0 = blockIdx.x * 64;
    if (row0 >= rcnt) return;
    int col0 = blockIdx.y * 64;
    int kbeg = blockIdx.z * 128;
    int t = threadIdx.x;
    int ty = t >> 4, tx = t & 15;
    int lr = t >> 2, kaoff = (t & 3) * 4;
    int grow = row0 + lr;
    bool rowValid = grow < rcnt;
    const float* rp;
    if (kbeg < 1024) rp = rowValid ? X + (size_t)list1[grow] * 1024 + kbeg : X;
    else             rp = rowValid ? hN0 + (size_t)grow * 1024 + (kbeg - 1024) : hN0;
    const float* Bp = B + (size_t)kbeg * 512 + col0;
    int bidx0 = t, bidx1 = t + 256;

    auto loadA = [&](int k) -> float4 {
        if (!rowValid) return make_float4(0.f, 0.f, 0.f, 0.f);
        return *(const float4*)(rp + k);
    };
    auto loadB = [&](int idx, int k0) -> float4 {
        int row = idx >> 4, c4 = (idx & 15) * 4;
        return *(const float4*)(Bp + (size_t)(k0 + row) * 512 + c4);
    };

    float4 pa0 = loadA(kaoff);
    float4 pa1 = loadA(kaoff + 16);
    float4 pb0 = loadB(bidx0, 0);
    float4 pb1 = loadB(bidx1, 0);

    float acc[4][4] = {};
    for (int k0 = 0; k0 < 128; k0 += 32) {
        As[kaoff + 0][lr] = pa0.x; As[kaoff + 1][lr] = pa0.y;
        As[kaoff + 2][lr] = pa0.z; As[kaoff + 3][lr] = pa0.w;
        As[kaoff + 16][lr] = pa1.x; As[kaoff + 17][lr] = pa1.y;
        As[kaoff + 18][lr] = pa1.z; As[kaoff + 19][lr] = pa1.w;
        *(float4*)&Bs[bidx0 >> 4][(bidx0 & 15) * 4] = pb0;
        *(float4*)&Bs[bidx1 >> 4][(bidx1 & 15) * 4] = pb1;
        __syncthreads();
        if (k0 + 32 < 128) {
            pa0 = loadA(k0 + 32 + kaoff);
            pa1 = loadA(k0 + 32 + kaoff + 16);
            pb0 = loadB(bidx0, k0 + 32);
            pb1 = loadB(bidx1, k0 + 32);
        }
#pragma unroll
        for (int kk = 0; kk < 32; kk++) {
            float4 a4 = *(const float4*)&As[kk][ty * 4];
            float4 b4 = *(const float4*)&Bs[kk][tx * 4];
            float a[4] = {a4.x, a4.y, a4.z, a4.w};
            float b[4] = {b4.x, b4.y, b4.z, b4.w};
#pragma unroll
            for (int i = 0; i < 4; i++)
#pragma unroll
                for (int j = 0; j < 4; j++) acc[i][j] += a[i] * b[j];
        }
        __syncthreads();
    }
#pragma unroll
    for (int i = 0; i < 4; i++) {
        int r = row0 + ty * 4 + i;
        if (r < rcnt) {
            float* Crow = C0p + ((size_t)blockIdx.z * MAXL1 + r) * 512 + col0 + tx * 4;
            *(float4*)Crow = make_float4(acc[i][0], acc[i][1], acc[i][2], acc[i][3]);
        }
    }
}

// ---------------- fused split-K reduce + bias + relu -> h1, fp32 layer-1 logits -> lgc1 --------
__global__ __launch_bounds__(256)
void k_bias_logits(const float* __restrict__ C0p, const float* __restrict__ lb0,
                   const float* __restrict__ aw1, const float* __restrict__ aq1,
                   float* __restrict__ h1, float* __restrict__ lgc1,
                   const int* __restrict__ cnt) {
    __shared__ float sh[512];
    __shared__ float red[4];
    int r = blockIdx.x;
    if (r >= *cnt) return;
    int t = threadIdx.x;
    float v0 = lb0[t], v1 = lb0[256 + t];
    const float* base = C0p + (size_t)r * 512;
#pragma unroll
    for (int z = 0; z < 16; z++) {
        v0 += base[(size_t)z * MAXL1 * 512 + t];
        v1 += base[(size_t)z * MAXL1 * 512 + 256 + t];
    }
    v0 = v0 > 0.f ? v0 : 0.f;
    v1 = v1 > 0.f ? v1 : 0.f;
    sh[t] = v0; sh[256 + t] = v1;
    h1[(size_t)r * 512 + t] = v0;
    h1[(size_t)r * 512 + 256 + t] = v1;
    __syncthreads();
    float dot = 0.f;
    for (int k = 0; k < 512; k += 4) {
        dot += sh[k + 0] * aw1[(size_t)(k + 0) * 256 + t]
             + sh[k + 1] * aw1[(size_t)(k + 1) * 256 + t]
             + sh[k + 2] * aw1[(size_t)(k + 2) * 256 + t]
             + sh[k + 3] * aw1[(size_t)(k + 3) * 256 + t];
    }
    float v = (dot > 0.f ? dot : 0.f) * aq1[t];
#pragma unroll
    for (int off = 1; off < 64; off <<= 1) v += __shfl_xor(v, off);
    if ((t & 63) == 0) red[t >> 6] = v;
    __syncthreads();
    if (t == 0) lgc1[r] = red[0] + red[1] + red[2] + red[3];
}

// ---------------- fused layer-1 tail: softmax(lgc1) agg + [h1|hN1]@lw1 + bias + relu -> h2 -----
// 16 blocks x 16 output cols; 16 k-slices x 64 over K=1024.
__global__ __launch_bounds__(256)
void k_tail1(const float* __restrict__ h1, const float* __restrict__ lgc1,
             const int* __restrict__ senders, const int* __restrict__ list2,
             const int* __restrict__ inv1, const int* __restrict__ cnts,
             const float* __restrict__ lw1, const float* __restrict__ lb1,
             float* __restrict__ h2) {
    __shared__ __align__(16) float As[17][1024];  // [j][0:512)=own h1 row, [512:1024)=hN1 row
    __shared__ float sw[17][16];
    __shared__ int   srow[17][16];
    __shared__ int   orow[17];
    __shared__ float psum[16][17 * 16];
    int c2 = cnts[2];
    int t = threadIdx.x;
    int b = blockIdx.x;

    for (int i = t; i < c2 * 16; i += 256) {
        int j = i >> 4, k = i & 15;
        int s = senders[list2[j] * DEG + k];
        int rr = inv1[s];
        srow[j][k] = rr;
        sw[j][k] = lgc1[rr];
    }
    if (t < c2) orow[t] = inv1[list2[t]];
    __syncthreads();
    if (t < c2) {
        float m = -1e30f;
        for (int k = 0; k < 16; k++) m = fmaxf(m, sw[t][k]);
        float d = 0.f;
        for (int k = 0; k < 16; k++) { float w = __expf(sw[t][k] - m); sw[t][k] = w; d += w; }
        float inv = 1.f / d;
        for (int k = 0; k < 16; k++) sw[t][k] *= inv;
    }
    __syncthreads();
    for (int e = t; e < c2 * 128; e += 256) {
        int j = e >> 7, d4 = (e & 127) * 4;
        *(float4*)&As[j][d4] = *(const float4*)&h1[(size_t)orow[j] * 512 + d4];
        float4 a = make_float4(0.f, 0.f, 0.f, 0.f);
#pragma unroll
        for (int k = 0; k < 16; k++) {
            float w = sw[j][k];
            float4 v = *(const float4*)&h1[(size_t)srow[j][k] * 512 + d4];
            a.x += w * v.x; a.y += w * v.y; a.z += w * v.z; a.w += w * v.w;
        }
        *(float4*)&As[j][512 + d4] = a;
    }
    __syncthreads();
    // GEMM: thread = (col c 0..15, k-slice s 0..15 of 64)
    int c = t & 15, s = t >> 4;
    int gc = b * 16 + c;
    float acc[17];
#pragma unroll
    for (int j = 0; j < 17; j++) acc[j] = 0.f;
    for (int k = s * 64; k < s * 64 + 64; k += 4) {
        float b0 = lw1[(size_t)(k + 0) * 256 + gc];
        float b1 = lw1[(size_t)(k + 1) * 256 + gc];
        float b2 = lw1[(size_t)(k + 2) * 256 + gc];
        float b3 = lw1[(size_t)(k + 3) * 256 + gc];
#pragma unroll
        for (int j = 0; j < 17; j++) {
            float4 a = *(const float4*)&As[j][k];
            acc[j] += a.x * b0 + a.y * b1 + a.z * b2 + a.w * b3;
        }
    }
#pragma unroll
    for (int j = 0; j < 17; j++) psum[s][j * 16 + c] = acc[j];
    __syncthreads();
    for (int e = t; e < c2 * 16; e += 256) {
        int j = e >> 4, cc = e & 15;
        float v = 0.f;
#pragma unroll
        for (int s2 = 0; s2 < 16; s2++) v += psum[s2][j * 16 + cc];
        v += lb1[b * 16 + cc];
        h2[(size_t)j * 256 + b * 16 + cc] = v > 0.f ? v : 0.f;
    }
}

// ---------------- fused layer-2 tail: logits2 + softmax + agg + [h2|hN2]@lw2 + out matvec ------
__global__ __launch_bounds__(512)
void k_tail2(const float* __restrict__ h2, const int* __restrict__ senders,
             const int* __restrict__ inv2, const int* __restrict__ cnts,
             const float* __restrict__ aw2, const float* __restrict__ aq2,
             const float* __restrict__ lw2, const float* __restrict__ lb2,
             const float* __restrict__ ow, const float* __restrict__ ob,
             float* __restrict__ out) {
    __shared__ __align__(16) float sh2[17][256];
    __shared__ __align__(16) float psum[8][17][128];
    __shared__ __align__(16) float h3in[512];
    __shared__ __align__(16) float sh3[128];
    __shared__ __align__(16) float psumB[16][128];
    __shared__ float slog[17];
    __shared__ float swt[16];
    __shared__ int   srow2[16];
    __shared__ int   srow14;
    int c2 = cnts[2];
    int t = threadIdx.x;
    for (int e = t; e < c2 * 64; e += 512) {
        int j = e >> 6, d4 = (e & 63) * 4;
        *(float4*)&sh2[j][d4] = *(const float4*)&h2[(size_t)j * 256 + d4];
    }
    if (t < c2) slog[t] = 0.f;
    if (t < 16) srow2[t] = inv2[senders[14 * DEG + t]];
    if (t == 31) srow14 = inv2[14];
    __syncthreads();
    {
        int cg = t & 31;
        int s  = (t >> 5) & 7;
        int jg = t >> 8;
        int j0 = jg * 9;
        int jend = min(c2, j0 + 9);
        float4 acc[9];
#pragma unroll
        for (int i = 0; i < 9; i++) acc[i] = make_float4(0.f, 0.f, 0.f, 0.f);
        const float* ap = aw2 + cg * 4;
        for (int k = s * 32; k < s * 32 + 32; k++) {
            float4 bv = *(const float4*)(ap + (size_t)k * 128);
#pragma unroll
            for (int i = 0; i < 9; i++) {
                int j = j0 + i;
                if (j < jend) {
                    float a = sh2[j][k];
                    acc[i].x += a * bv.x; acc[i].y += a * bv.y;
                    acc[i].z += a * bv.z; acc[i].w += a * bv.w;
                }
            }
        }
#pragma unroll
        for (int i = 0; i < 9; i++) {
            int j = j0 + i;
            if (j < jend) *(float4*)&psum[s][j][cg * 4] = acc[i];
        }
    }
    __syncthreads();
    for (int e = t; e < c2 * 128; e += 512) {
        int j = e >> 7, c = e & 127;
        float v = 0.f;
#pragma unroll
        for (int s = 0; s < 8; s++) v += psum[s][j][c];
        v = v > 0.f ? v : 0.f;
        atomicAdd(&slog[j], v * aq2[c]);
    }
    __syncthreads();
    if (t == 0) {
        float m = -1e30f;
        for (int k = 0; k < 16; k++) m = fmaxf(m, slog[srow2[k]]);
        float d = 0.f;
        for (int k = 0; k < 16; k++) { float w = __expf(slog[srow2[k]] - m); swt[k] = w; d += w; }
        float inv = 1.f / d;
        for (int k = 0; k < 16; k++) swt[k] *= inv;
    }
    __syncthreads();
    if (t < 256) {
        float a = 0.f;
#pragma unroll
        for (int k = 0; k < 16; k++) a += swt[k] * sh2[srow2[k]][t];
        h3in[256 + t] = a;
    } else {
        int d = t - 256;
        h3in[d] = sh2[srow14][d];
    }
    __syncthreads();
    {
        int cg = t & 31, s = t >> 5;
        float4 acc = make_float4(0.f, 0.f, 0.f, 0.f);
        const float* bp = lw2 + cg * 4;
        for (int k = s * 32; k < s * 32 + 32; k++) {
            float4 bv = *(const float4*)(bp + (size_t)k * 128);
            float a = h3in[k];
            acc.x += a * bv.x; acc.y += a * bv.y; acc.z += a * bv.z; acc.w += a * bv.w;
        }
        *(float4*)&psumB[s][cg * 4] = acc;
    }
    __syncthreads();
    if (t < 128) {
        float v = lb2[t];
#pragma unroll
        for (int s = 0; s < 16; s++) v += psumB[s][t];
        sh3[t] = v > 0.f ? v : 0.f;
    }
    __syncthreads();
    {
        int cg = t & 31, s = t >> 5;
        float4 acc = make_float4(0.f, 0.f, 0.f, 0.f);
        const float* bp = ow + cg * 4;
        for (int k = s * 8; k < s * 8 + 8; k++) {
            float4 bv = *(const float4*)(bp + (size_t)k * 128);
            float a = sh3[k];
            acc.x += a * bv.x; acc.y += a * bv.y; acc.z += a * bv.z; acc.w += a * bv.w;
        }
        *(float4*)&psumB[s][cg * 4] = acc;
    }
    __syncthreads();
    if (t < 128) {
        float v = ob[t];
#pragma unroll
        for (int s = 0; s < 16; s++) v += psumB[s][t];
        out[t] = v;
    }
}

// ---------------- launch ----------------
extern "C" void kernel_launch(void* const* d_in, const int* in_sizes, int n_in,
                              void* d_out, int out_size, void* d_ws, size_t ws_size,
                              hipStream_t stream) {
    const float* X       = (const float*)d_in[0];
    const int*   senders = (const int*)d_in[1];
    const float* lw0 = (const float*)d_in[3];
    const float* lb0 = (const float*)d_in[4];
    const float* aw0 = (const float*)d_in[5];
    const float* aq0 = (const float*)d_in[6];
    const float* lw1 = (const float*)d_in[7];
    const float* lb1 = (const float*)d_in[8];
    const float* aw1 = (const float*)d_in[9];
    const float* aq1 = (const float*)d_in[10];
    const float* lw2 = (const float*)d_in[11];
    const float* lb2 = (const float*)d_in[12];
    const float* aw2 = (const float*)d_in[13];
    const float* aq2 = (const float*)d_in[14];
    const float* owp = (const float*)d_in[15];
    const float* obp = (const float*)d_in[16];
    float* out = (float*)d_out;

    char* ws = (char*)d_ws;
    size_t off = 0;
    auto alloc = [&](size_t nbytes) -> void* {
        void* p = ws + off;
        off += (nbytes + 255) & ~(size_t)255;
        return p;
    };
    // ---- zero region (zeroed by k_frontier): lgc0 only ----
    float* lgc0 = (float*)alloc(L0PAD * 4);
    size_t zero_end = off;
    // ---- rest (poisoned; every read site written first) ----
    float* lgc1 = (float*)alloc(MAXL1 * 4);
    int* inv1  = (int*)alloc(NN * 4);
    int* inv2  = (int*)alloc(NN * 4);
    int* list1 = (int*)alloc(MAXL1 * 4);
    int* list2 = (int*)alloc(MAXL2 * 4);
    int* cnts  = (int*)alloc(16);
    float* dummy = (float*)alloc(16);
    ushort_t* Xg  = (ushort_t*)alloc((size_t)L0PAD * 1024 * 2);    // staged bf16 A
    ushort_t* awT = (ushort_t*)alloc((size_t)512 * 1024 * 2);      // aw0^T bf16 [512][1024]
    float* C0p  = (float*)alloc((size_t)16 * MAXL1 * 512 * 4);     // split-K partials
    float* hN0c = (float*)alloc((size_t)MAXL1 * 1024 * 4);
    float* h1c  = (float*)alloc((size_t)MAXL1 * 512 * 4);
    float* h2c  = (float*)alloc((size_t)MAXL2 * 256 * 4);
    (void)in_sizes; (void)n_in; (void)out_size; (void)ws_size;

    int nz4 = (int)(zero_end / 16);
    int nzb = (nz4 + 255) / 256;

    // 1. BFS 2+1 || zero lgc0 || transpose aw0 || warm tail weights
    hipLaunchKernelGGL(k_frontier, dim3(1 + nzb + 512 + 124), dim3(256), 0, stream,
                       senders, list2, inv2, list1, inv1, cnts,
                       aw0, awT, aw1, lw1, aw2, lw2, owp, dummy,
                       (float4*)ws, nz4, nzb);
    // 2. gather X -> bf16 Xg (staged once; 8 col-blocks then reuse it from L3)
    hipLaunchKernelGGL(k_prep, dim3(L0PAD), dim3(256), 0, stream,
                       X, senders, list1, cnts, Xg);
    // 3. layer-0 logits (bf16 MFMA over Xg, grid 73x8)
    hipLaunchKernelGGL(k_logits_mfma, dim3(73, 8), dim3(256), 0, stream,
                       Xg, awT, aq0, lgc0, cnts + 0);
    // 4. layer-0 attention aggregate
    hipLaunchKernelGGL(k_agg0, dim3(MAXL1), dim3(256), 0, stream,
                       X, lgc0, senders, list1, cnts + 1, hN0c);
    // 5. mm0: [X|hN0] @ lw0, split-K 16, direct partial stores
    hipLaunchKernelGGL(k_mm0, dim3(5, 8, 16), dim3(256), 0, stream,
                       X, hN0c, list1, lw0, C0p, cnts + 1);
    // 6. fused reduce + bias + relu -> h1, fp32 layer-1 logits -> lgc1
    hipLaunchKernelGGL(k_bias_logits, dim3(MAXL1), dim3(256), 0, stream,
                       C0p, lb0, aw1, aq1, h1c, lgc1, cnts + 1);
    // 7. fused layer-1 tail -> h2 (17x256)
    hipLaunchKernelGGL(k_tail1, dim3(16), dim3(256), 0, stream,
                       h1c, lgc1, senders, list2, inv1, cnts, lw1, lb1, h2c);
    // 8. fused layer-2 tail -> out (128)
    hipLaunchKernelGGL(k_tail2, dim3(1), dim3(512), 0, stream,
                       h2c, senders, inv2, cnts, aw2, aq2, lw2, lb2, owp, obp, out);
}